// Round 1
// baseline (1249.891 us; speedup 1.0000x reference)
//
#include <hip/hip_runtime.h>
#include <hip/hip_bf16.h>

using u16 = unsigned short;
typedef __bf16 bf16x8_t __attribute__((ext_vector_type(8)));
typedef float    f32x4  __attribute__((ext_vector_type(4)));
typedef unsigned short u16x8 __attribute__((ext_vector_type(8)));

#define B_  64
#define L_  1024
#define TOT 65536
#define D_  512
#define H_  2048
#define NH_ 8

__device__ __forceinline__ float b2f(u16 x) {
    union { unsigned int i; float f; } v; v.i = ((unsigned int)x) << 16; return v.f;
}
__device__ __forceinline__ u16 f2b(float f) {
    union { float f; unsigned int i; } v; v.f = f;
    unsigned int i = v.i;
    unsigned int r = i + 0x7FFFu + ((i >> 16) & 1u);   // RNE
    return (u16)(r >> 16);
}

// ---------------- transpose + fp32->bf16 convert:  in[R][C] f32 -> out[C][R] bf16
__global__ __launch_bounds__(256) void transpose_cvt(const float* __restrict__ in,
                                                     u16* __restrict__ out, int R, int C) {
    __shared__ float tile[32][33];
    int c0 = blockIdx.x * 32, r0 = blockIdx.y * 32;
    int tx = threadIdx.x, ty = threadIdx.y;
    #pragma unroll
    for (int i = 0; i < 4; ++i)
        tile[ty + 8 * i][tx] = in[(size_t)(r0 + ty + 8 * i) * C + c0 + tx];
    __syncthreads();
    #pragma unroll
    for (int i = 0; i < 4; ++i)
        out[(size_t)(c0 + ty + 8 * i) * R + r0 + tx] = f2b(tile[tx][ty + 8 * i]);
}

// ---------------- qp = q @ Wq + bq   (512 outputs, 2 blocks)
__global__ __launch_bounds__(256) void qp_kernel(const float* __restrict__ q,
                                                 const float* __restrict__ Wq,
                                                 const float* __restrict__ bq,
                                                 float* __restrict__ qp) {
    __shared__ float qs[512];
    int tid = threadIdx.x;
    qs[tid] = q[tid]; qs[tid + 256] = q[tid + 256];
    __syncthreads();
    int j = blockIdx.x * 256 + tid;
    float acc = bq[j];
    for (int d = 0; d < 512; ++d) acc += qs[d] * Wq[(size_t)d * 512 + j];
    qp[j] = acc;
}

// ---------------- wke[d][h] = 0.125 * sum_j Wk[d, h*64+j]*qp[h*64+j];  cke[h] likewise from bk
__global__ __launch_bounds__(256) void wke_kernel(const float* __restrict__ Wk,
                                                  const float* __restrict__ bk,
                                                  const float* __restrict__ qp,
                                                  float* __restrict__ wke,
                                                  float* __restrict__ cke) {
    __shared__ float qs[512];
    int tid = threadIdx.x;
    qs[tid] = qp[tid]; qs[tid + 256] = qp[tid + 256];
    __syncthreads();
    int d = blockIdx.x * 32 + (tid >> 3);
    int h = tid & 7;
    float s = 0.f;
    for (int j = 0; j < 64; ++j) s += Wk[(size_t)d * 512 + h * 64 + j] * qs[h * 64 + j];
    wke[d * 8 + h] = 0.125f * s;
    if (blockIdx.x == 0 && tid < 8) {
        float c = 0.f;
        for (int j = 0; j < 64; ++j) c += bk[tid * 64 + j] * qs[tid * 64 + j];
        cke[tid] = 0.125f * c;
    }
}

// ---------------- gather emb rows -> bf16 z chunk
__global__ __launch_bounds__(256) void embed_kernel(const int* __restrict__ idx,
                                                    const float* __restrict__ emb,
                                                    u16* __restrict__ z) {
    int u = blockIdx.x * 256 + threadIdx.x;   // one unit = 8 elements
    int t = u >> 6;                            // 64 units per 512-wide row
    int d0 = (u & 63) * 8;
    int row = idx[t];
    const float4* src = (const float4*)(emb + (size_t)row * 512 + d0);
    float4 a = src[0], b = src[1];
    u16x8 o;
    o[0] = f2b(a.x); o[1] = f2b(a.y); o[2] = f2b(a.z); o[3] = f2b(a.w);
    o[4] = f2b(b.x); o[5] = f2b(b.y); o[6] = f2b(b.z); o[7] = f2b(b.w);
    *(u16x8*)(z + (size_t)t * 512 + d0) = o;
}

// ---------------- m97-style bf16 GEMM:  C[M,N] = act(A[M,K] @ Bt[N,K]^T + bias)
template <int RELU>
__global__ __launch_bounds__(256) void gemm_bt(const u16* __restrict__ A,
                                               const u16* __restrict__ Bt,
                                               const float* __restrict__ bias,
                                               u16* __restrict__ C,
                                               int N, int K) {
    __shared__ __align__(16) u16 As[128 * 32];
    __shared__ __align__(16) u16 Bs[128 * 32];
    const int tid = threadIdx.x;
    const int m0 = blockIdx.y * 128, n0 = blockIdx.x * 128;
    const int lane = tid & 63, quad = lane >> 4, l15 = lane & 15;
    const int wave = tid >> 6, wm = wave >> 1, wn = wave & 1;

    f32x4 acc[4][4] = {};

    const int nK = K >> 5;
    for (int kt = 0; kt < nK; ++kt) {
        __syncthreads();
        const int kb = kt * 32;
        #pragma unroll
        for (int r = 0; r < 2; ++r) {
            int u = tid + r * 256;
            const u16* ga = A + (size_t)(m0 + (u >> 2)) * K + kb + (u & 3) * 8;
            __builtin_amdgcn_global_load_lds((const __attribute__((address_space(1))) void*)ga,
                                             (__attribute__((address_space(3))) void*)(&As[u * 8]),
                                             16, 0, 0);
            const u16* gb = Bt + (size_t)(n0 + (u >> 2)) * K + kb + (u & 3) * 8;
            __builtin_amdgcn_global_load_lds((const __attribute__((address_space(1))) void*)gb,
                                             (__attribute__((address_space(3))) void*)(&Bs[u * 8]),
                                             16, 0, 0);
        }
        __syncthreads();
        bf16x8_t af[4], bfr[4];
        #pragma unroll
        for (int mt = 0; mt < 4; ++mt)
            af[mt] = *(const bf16x8_t*)&As[(wm * 64 + mt * 16 + l15) * 32 + quad * 8];
        #pragma unroll
        for (int nt = 0; nt < 4; ++nt)
            bfr[nt] = *(const bf16x8_t*)&Bs[(wn * 64 + nt * 16 + l15) * 32 + quad * 8];
        #pragma unroll
        for (int mt = 0; mt < 4; ++mt)
            #pragma unroll
            for (int nt = 0; nt < 4; ++nt)
                acc[mt][nt] = __builtin_amdgcn_mfma_f32_16x16x32_bf16(af[mt], bfr[nt],
                                                                      acc[mt][nt], 0, 0, 0);
    }

    float bvv[4];
    #pragma unroll
    for (int nt = 0; nt < 4; ++nt) bvv[nt] = bias[n0 + wn * 64 + nt * 16 + l15];
    #pragma unroll
    for (int mt = 0; mt < 4; ++mt)
        #pragma unroll
        for (int nt = 0; nt < 4; ++nt)
            #pragma unroll
            for (int r = 0; r < 4; ++r) {
                int row = m0 + wm * 64 + mt * 16 + quad * 4 + r;
                int col = n0 + wn * 64 + nt * 16 + l15;
                float v = acc[mt][nt][r] + bvv[nt];
                if (RELU) v = fmaxf(v, 0.f);
                C[(size_t)row * N + col] = f2b(v);
            }
}

// ---------------- per-set: scores -> softmax -> u[b,h,:] = sum_l a*h
__global__ __launch_bounds__(512) void attn_kernel(const u16* __restrict__ h,
                                                   const float* __restrict__ wke,
                                                   const float* __restrict__ cke,
                                                   float* __restrict__ u) {
    __shared__ float sc[8][1024];
    const int b = blockIdx.x, tid = threadIdx.x;
    const int w = tid >> 6, lane = tid & 63;

    float wkr[8][8];
    #pragma unroll
    for (int j = 0; j < 8; ++j)
        #pragma unroll
        for (int hh = 0; hh < 8; ++hh) wkr[j][hh] = wke[(lane * 8 + j) * 8 + hh];
    float cr[8];
    #pragma unroll
    for (int hh = 0; hh < 8; ++hh) cr[hh] = cke[hh];

    const u16* hb = h + (size_t)b * 1024 * 512;

    for (int l = w; l < 1024; l += 8) {
        u16x8 hv = *(const u16x8*)(hb + (size_t)l * 512 + lane * 8);
        float s[8] = {0, 0, 0, 0, 0, 0, 0, 0};
        #pragma unroll
        for (int j = 0; j < 8; ++j) {
            float hf = b2f(hv[j]);
            #pragma unroll
            for (int hh = 0; hh < 8; ++hh) s[hh] += hf * wkr[j][hh];
        }
        #pragma unroll
        for (int hh = 0; hh < 8; ++hh) {
            float v = s[hh];
            for (int off = 32; off; off >>= 1) v += __shfl_xor(v, off, 64);
            if (lane == 0) sc[hh][l] = v + cr[hh];
        }
    }
    __syncthreads();
    // softmax: wave w handles head w
    {
        float m = -1e30f;
        for (int l = lane; l < 1024; l += 64) m = fmaxf(m, sc[w][l]);
        for (int off = 32; off; off >>= 1) m = fmaxf(m, __shfl_xor(m, off, 64));
        float ssum = 0.f;
        for (int l = lane; l < 1024; l += 64) {
            float e = __expf(sc[w][l] - m); sc[w][l] = e; ssum += e;
        }
        for (int off = 32; off; off >>= 1) ssum += __shfl_xor(ssum, off, 64);
        float inv = 1.f / ssum;
        for (int l = lane; l < 1024; l += 64) sc[w][l] *= inv;
    }
    __syncthreads();
    // u accumulation: thread owns one d
    float acc[8] = {0, 0, 0, 0, 0, 0, 0, 0};
    const int d = tid;
    for (int l = 0; l < 1024; ++l) {
        float hf = b2f(hb[(size_t)l * 512 + d]);
        #pragma unroll
        for (int hh = 0; hh < 8; ++hh) acc[hh] += sc[hh][l] * hf;
    }
    #pragma unroll
    for (int hh = 0; hh < 8; ++hh) u[((size_t)b * 8 + hh) * 512 + d] = acc[hh];
}

// ---------------- per-set: ctx = u@Wv_blocks + bv; pooled = ctx@Wo + bo; LN -> y
__global__ __launch_bounds__(256) void pool_kernel(const float* __restrict__ u,
                                                   const float* __restrict__ Wv,
                                                   const float* __restrict__ bv,
                                                   const float* __restrict__ Wo,
                                                   const float* __restrict__ bo,
                                                   const float* __restrict__ g,
                                                   const float* __restrict__ lb,
                                                   float* __restrict__ y) {
    __shared__ float us[8 * 512];
    __shared__ float ctx[512];
    __shared__ float red[8];
    __shared__ float stats[2];
    const int b = blockIdx.x, tid = threadIdx.x;
    for (int i = tid; i < 4096; i += 256) us[i] = u[(size_t)b * 4096 + i];
    __syncthreads();
    #pragma unroll
    for (int ph = 0; ph < 2; ++ph) {
        int e = tid + ph * 256;
        int hh = e >> 6;
        float acc = bv[e];
        for (int dd = 0; dd < 512; ++dd) acc += us[hh * 512 + dd] * Wv[(size_t)dd * 512 + e];
        ctx[e] = acc;
    }
    __syncthreads();
    float pv[2]; float psum = 0.f, psq = 0.f;
    #pragma unroll
    for (int ph = 0; ph < 2; ++ph) {
        int e2 = tid + ph * 256;
        float acc = bo[e2];
        for (int ee = 0; ee < 512; ++ee) acc += ctx[ee] * Wo[(size_t)ee * 512 + e2];
        pv[ph] = acc; psum += acc; psq += acc * acc;
    }
    for (int off = 32; off; off >>= 1) { psum += __shfl_xor(psum, off, 64); psq += __shfl_xor(psq, off, 64); }
    const int w = tid >> 6, lane = tid & 63;
    if (lane == 0) { red[w] = psum; red[4 + w] = psq; }
    __syncthreads();
    if (tid == 0) {
        float s = red[0] + red[1] + red[2] + red[3];
        float q2 = red[4] + red[5] + red[6] + red[7];
        float mu = s / 512.f;
        float var = q2 / 512.f - mu * mu;
        stats[0] = mu; stats[1] = 1.f / sqrtf(var + 1e-5f);
    }
    __syncthreads();
    #pragma unroll
    for (int ph = 0; ph < 2; ++ph) {
        int e2 = tid + ph * 256;
        y[(size_t)b * 512 + e2] = (pv[ph] - stats[0]) * stats[1] * g[e2] + lb[e2];
    }
}

// ---------------- head MLP layer 1: hid = relu(y@Wh1 + bh1)
__global__ __launch_bounds__(256) void h1_kernel(const float* __restrict__ y,
                                                 const float* __restrict__ Wh1,
                                                 const float* __restrict__ bh1,
                                                 float* __restrict__ hid) {
    __shared__ float ys[512];
    const int b = blockIdx.y, tid = threadIdx.x;
    ys[tid] = y[(size_t)b * 512 + tid];
    ys[tid + 256] = y[(size_t)b * 512 + tid + 256];
    __syncthreads();
    int j = blockIdx.x * 256 + tid;
    float acc = bh1[j];
    for (int dd = 0; dd < 512; ++dd) acc += ys[dd] * Wh1[(size_t)dd * 2048 + j];
    hid[(size_t)b * 2048 + j] = fmaxf(acc, 0.f);
}

// ---------------- head MLP layer 2: logits = hid@Wh2 + bh2
__global__ __launch_bounds__(256) void h2_kernel(const float* __restrict__ hid,
                                                 const float* __restrict__ Wh2,
                                                 const float* __restrict__ bh2,
                                                 float* __restrict__ out) {
    __shared__ float red[4];
    const int b = blockIdx.x, tid = threadIdx.x;
    float s = 0.f;
    for (int j = tid; j < 2048; j += 256) s += hid[(size_t)b * 2048 + j] * Wh2[j];
    for (int off = 32; off; off >>= 1) s += __shfl_xor(s, off, 64);
    const int w = tid >> 6, lane = tid & 63;
    if (lane == 0) red[w] = s;
    __syncthreads();
    if (tid == 0) out[b] = red[0] + red[1] + red[2] + red[3] + bh2[0];
}

extern "C" void kernel_launch(void* const* d_in, const int* in_sizes, int n_in,
                              void* d_out, int out_size, void* d_ws, size_t ws_size,
                              hipStream_t stream) {
    const int*   mut_idx = (const int*)d_in[0];
    const float* emb  = (const float*)d_in[2];
    const float* W1   = (const float*)d_in[3];
    const float* b1   = (const float*)d_in[4];
    const float* W2   = (const float*)d_in[5];
    const float* b2   = (const float*)d_in[6];
    const float* q    = (const float*)d_in[7];
    const float* Wq   = (const float*)d_in[8];
    const float* bq   = (const float*)d_in[9];
    const float* Wk   = (const float*)d_in[10];
    const float* bk   = (const float*)d_in[11];
    const float* Wv   = (const float*)d_in[12];
    const float* bv   = (const float*)d_in[13];
    const float* Wo   = (const float*)d_in[14];
    const float* bo   = (const float*)d_in[15];
    const float* ln_g = (const float*)d_in[16];
    const float* ln_b = (const float*)d_in[17];
    const float* Wh1  = (const float*)d_in[18];
    const float* bh1  = (const float*)d_in[19];
    const float* Wh2  = (const float*)d_in[20];
    const float* bh2  = (const float*)d_in[21];
    float* out = (float*)d_out;

    // fixed-footprint allocations (256B aligned)
    char* p = (char*)d_ws;
    auto alloc = [&](size_t bytes) {
        char* r = p; p += (bytes + 255) & ~(size_t)255; return r;
    };
    u16*  W1t  = (u16*)alloc((size_t)H_ * D_ * 2);      // [2048][512] bf16
    u16*  W2t  = (u16*)alloc((size_t)D_ * H_ * 2);      // [512][2048] bf16
    float* qp  = (float*)alloc(D_ * 4);
    float* wke = (float*)alloc((size_t)D_ * NH_ * 4);
    float* cke = (float*)alloc(NH_ * 4);
    float* ubuf = (float*)alloc((size_t)B_ * NH_ * D_ * 4);
    float* ybuf = (float*)alloc((size_t)B_ * D_ * 4);
    float* hid  = (float*)alloc((size_t)B_ * H_ * 4);
    u16*  hbuf = (u16*)alloc((size_t)TOT * D_ * 2);     // full h, bf16

    size_t fixed = (size_t)(p - (char*)d_ws);
    // adaptive chunk: z (CH*1024 B) + C1 (CH*4096 B)
    int CH = 16384;
    while (CH > 1024 && fixed + (size_t)CH * 5120 + 8192 > ws_size) CH >>= 1;
    u16* z  = (u16*)alloc((size_t)CH * D_ * 2);
    u16* C1 = (u16*)alloc((size_t)CH * H_ * 2);

    // weight conversion / folding
    transpose_cvt<<<dim3(H_ / 32, D_ / 32), dim3(32, 8), 0, stream>>>(W1, W1t, D_, H_);
    transpose_cvt<<<dim3(D_ / 32, H_ / 32), dim3(32, 8), 0, stream>>>(W2, W2t, H_, D_);
    qp_kernel<<<2, 256, 0, stream>>>(q, Wq, bq, qp);
    wke_kernel<<<16, 256, 0, stream>>>(Wk, bk, qp, wke, cke);

    // phi MLP over token chunks
    for (int c = 0; c * CH < TOT; ++c) {
        embed_kernel<<<CH / 4, 256, 0, stream>>>(mut_idx + c * CH, emb, z);
        gemm_bt<1><<<dim3(H_ / 128, CH / 128), 256, 0, stream>>>(z, W1t, b1, C1, H_, D_);
        gemm_bt<0><<<dim3(D_ / 128, CH / 128), 256, 0, stream>>>(C1, W2t, b2,
                                                                 hbuf + (size_t)c * CH * D_, D_, H_);
    }

    // attention pool + head
    attn_kernel<<<B_, 512, 0, stream>>>(hbuf, wke, cke, ubuf);
    pool_kernel<<<B_, 256, 0, stream>>>(ubuf, Wv, bv, Wo, bo, ln_g, ln_b, ybuf);
    h1_kernel<<<dim3(H_ / 256, B_), 256, 0, stream>>>(ybuf, Wh1, bh1, hid);
    h2_kernel<<<B_, 256, 0, stream>>>(hid, Wh2, bh2, out);
}

// Round 2
// 948.508 us; speedup vs baseline: 1.3177x; 1.3177x over previous
//
#include <hip/hip_runtime.h>
#include <hip/hip_bf16.h>

using u16 = unsigned short;
typedef __bf16 bf16x8_t __attribute__((ext_vector_type(8)));
typedef float    f32x4  __attribute__((ext_vector_type(4)));
typedef unsigned short u16x8 __attribute__((ext_vector_type(8)));

#define B_  64
#define L_  1024
#define TOT 65536
#define D_  512
#define H_  2048
#define NH_ 8

__device__ __forceinline__ float b2f(u16 x) {
    union { unsigned int i; float f; } v; v.i = ((unsigned int)x) << 16; return v.f;
}
__device__ __forceinline__ u16 f2b(float f) {
    union { float f; unsigned int i; } v; v.f = f;
    unsigned int i = v.i;
    unsigned int r = i + 0x7FFFu + ((i >> 16) & 1u);   // RNE
    return (u16)(r >> 16);
}

// ---------------- transpose + fp32->bf16 convert:  in[R][C] f32 -> out[C][R] bf16
__global__ __launch_bounds__(256) void transpose_cvt(const float* __restrict__ in,
                                                     u16* __restrict__ out, int R, int C) {
    __shared__ float tile[32][33];
    int c0 = blockIdx.x * 32, r0 = blockIdx.y * 32;
    int tx = threadIdx.x, ty = threadIdx.y;
    #pragma unroll
    for (int i = 0; i < 4; ++i)
        tile[ty + 8 * i][tx] = in[(size_t)(r0 + ty + 8 * i) * C + c0 + tx];
    __syncthreads();
    #pragma unroll
    for (int i = 0; i < 4; ++i)
        out[(size_t)(c0 + ty + 8 * i) * R + r0 + tx] = f2b(tile[tx][ty + 8 * i]);
}

// ---------------- qp = q @ Wq + bq   (512 outputs, 2 blocks)
__global__ __launch_bounds__(256) void qp_kernel(const float* __restrict__ q,
                                                 const float* __restrict__ Wq,
                                                 const float* __restrict__ bq,
                                                 float* __restrict__ qp) {
    __shared__ float qs[512];
    int tid = threadIdx.x;
    qs[tid] = q[tid]; qs[tid + 256] = q[tid + 256];
    __syncthreads();
    int j = blockIdx.x * 256 + tid;
    float acc = bq[j];
    for (int d = 0; d < 512; ++d) acc += qs[d] * Wq[(size_t)d * 512 + j];
    qp[j] = acc;
}

// ---------------- wke[d][h] = 0.125 * sum_j Wk[d, h*64+j]*qp[h*64+j];  cke[h] from bk
__global__ __launch_bounds__(256) void wke_kernel(const float* __restrict__ Wk,
                                                  const float* __restrict__ bk,
                                                  const float* __restrict__ qp,
                                                  float* __restrict__ wke,
                                                  float* __restrict__ cke) {
    __shared__ float qs[512];
    int tid = threadIdx.x;
    qs[tid] = qp[tid]; qs[tid + 256] = qp[tid + 256];
    __syncthreads();
    int d = blockIdx.x * 32 + (tid >> 3);
    int h = tid & 7;
    float s = 0.f;
    for (int j = 0; j < 64; ++j) s += Wk[(size_t)d * 512 + h * 64 + j] * qs[h * 64 + j];
    wke[d * 8 + h] = 0.125f * s;
    if (blockIdx.x == 0 && tid < 8) {
        float c = 0.f;
        for (int j = 0; j < 64; ++j) c += bk[tid * 64 + j] * qs[tid * 64 + j];
        cke[tid] = 0.125f * c;
    }
}

// ---------------- gather emb rows -> bf16 z chunk
__global__ __launch_bounds__(256) void embed_kernel(const int* __restrict__ idx,
                                                    const float* __restrict__ emb,
                                                    u16* __restrict__ z) {
    int u = blockIdx.x * 256 + threadIdx.x;   // one unit = 8 elements
    int t = u >> 6;                            // 64 units per 512-wide row
    int d0 = (u & 63) * 8;
    int row = idx[t];
    const float4* src = (const float4*)(emb + (size_t)row * 512 + d0);
    float4 a = src[0], b = src[1];
    u16x8 o;
    o[0] = f2b(a.x); o[1] = f2b(a.y); o[2] = f2b(a.z); o[3] = f2b(a.w);
    o[4] = f2b(b.x); o[5] = f2b(b.y); o[6] = f2b(b.z); o[7] = f2b(b.w);
    *(u16x8*)(z + (size_t)t * 512 + d0) = o;
}

// ---------------- m97-style bf16 GEMM:  C[M,N] = act(A[M,K] @ Bt[N,K]^T + bias)
template <int RELU>
__global__ __launch_bounds__(256) void gemm_bt(const u16* __restrict__ A,
                                               const u16* __restrict__ Bt,
                                               const float* __restrict__ bias,
                                               u16* __restrict__ C,
                                               int N, int K) {
    __shared__ __align__(16) u16 As[128 * 32];
    __shared__ __align__(16) u16 Bs[128 * 32];
    const int tid = threadIdx.x;
    const int m0 = blockIdx.y * 128, n0 = blockIdx.x * 128;
    const int lane = tid & 63, quad = lane >> 4, l15 = lane & 15;
    const int wave = tid >> 6, wm = wave >> 1, wn = wave & 1;

    f32x4 acc[4][4] = {};

    const int nK = K >> 5;
    for (int kt = 0; kt < nK; ++kt) {
        __syncthreads();
        const int kb = kt * 32;
        #pragma unroll
        for (int r = 0; r < 2; ++r) {
            int u = tid + r * 256;
            const u16* ga = A + (size_t)(m0 + (u >> 2)) * K + kb + (u & 3) * 8;
            __builtin_amdgcn_global_load_lds((const __attribute__((address_space(1))) void*)ga,
                                             (__attribute__((address_space(3))) void*)(&As[u * 8]),
                                             16, 0, 0);
            const u16* gb = Bt + (size_t)(n0 + (u >> 2)) * K + kb + (u & 3) * 8;
            __builtin_amdgcn_global_load_lds((const __attribute__((address_space(1))) void*)gb,
                                             (__attribute__((address_space(3))) void*)(&Bs[u * 8]),
                                             16, 0, 0);
        }
        __syncthreads();
        bf16x8_t af[4], bfr[4];
        #pragma unroll
        for (int mt = 0; mt < 4; ++mt)
            af[mt] = *(const bf16x8_t*)&As[(wm * 64 + mt * 16 + l15) * 32 + quad * 8];
        #pragma unroll
        for (int nt = 0; nt < 4; ++nt)
            bfr[nt] = *(const bf16x8_t*)&Bs[(wn * 64 + nt * 16 + l15) * 32 + quad * 8];
        #pragma unroll
        for (int mt = 0; mt < 4; ++mt)
            #pragma unroll
            for (int nt = 0; nt < 4; ++nt)
                acc[mt][nt] = __builtin_amdgcn_mfma_f32_16x16x32_bf16(af[mt], bfr[nt],
                                                                      acc[mt][nt], 0, 0, 0);
    }

    float bvv[4];
    #pragma unroll
    for (int nt = 0; nt < 4; ++nt) bvv[nt] = bias[n0 + wn * 64 + nt * 16 + l15];
    #pragma unroll
    for (int mt = 0; mt < 4; ++mt)
        #pragma unroll
        for (int nt = 0; nt < 4; ++nt)
            #pragma unroll
            for (int r = 0; r < 4; ++r) {
                int row = m0 + wm * 64 + mt * 16 + quad * 4 + r;
                int col = n0 + wn * 64 + nt * 16 + l15;
                float v = acc[mt][nt][r] + bvv[nt];
                if (RELU) v = fmaxf(v, 0.f);
                C[(size_t)row * N + col] = f2b(v);
            }
}

// ---------------- scores[b][h][l] = h[b,l,:] . wke[:,h] + cke[h]
// grid (16, 64): x = l-chunk of 64, y = b.  wave w handles 16 l's.
__global__ __launch_bounds__(256) void score_kernel(const u16* __restrict__ h,
                                                    const float* __restrict__ wke,
                                                    const float* __restrict__ cke,
                                                    float* __restrict__ scb) {
    const int b = blockIdx.y, lc = blockIdx.x, tid = threadIdx.x;
    const int w = tid >> 6, lane = tid & 63;

    float wkr[8][8];
    #pragma unroll
    for (int j = 0; j < 8; ++j)
        #pragma unroll
        for (int hh = 0; hh < 8; ++hh) wkr[j][hh] = wke[(lane * 8 + j) * 8 + hh];
    float cr[8];
    #pragma unroll
    for (int hh = 0; hh < 8; ++hh) cr[hh] = cke[hh];

    const u16* hb = h + (size_t)b * 1024 * 512;

    #pragma unroll 2
    for (int i = 0; i < 16; ++i) {
        int l = lc * 64 + w * 16 + i;
        u16x8 hv = *(const u16x8*)(hb + (size_t)l * 512 + lane * 8);
        float s[8] = {0, 0, 0, 0, 0, 0, 0, 0};
        #pragma unroll
        for (int j = 0; j < 8; ++j) {
            float hf = b2f(hv[j]);
            #pragma unroll
            for (int hh = 0; hh < 8; ++hh) s[hh] += hf * wkr[j][hh];
        }
        #pragma unroll
        for (int hh = 0; hh < 8; ++hh) {
            float v = s[hh];
            for (int off = 32; off; off >>= 1) v += __shfl_xor(v, off, 64);
            if (lane == 0) scb[((size_t)b * 8 + hh) * 1024 + l] = v + cr[hh];
        }
    }
}

// ---------------- softmax over l for each (b,h); in-place on scb. grid 512.
__global__ __launch_bounds__(256) void softmax_kernel(float* __restrict__ scb) {
    __shared__ float red[8];
    const int bh = blockIdx.x, tid = threadIdx.x;
    const int w = tid >> 6, lane = tid & 63;
    float* p = scb + (size_t)bh * 1024;
    float4 v = ((float4*)p)[tid];
    float m = fmaxf(fmaxf(v.x, v.y), fmaxf(v.z, v.w));
    for (int off = 32; off; off >>= 1) m = fmaxf(m, __shfl_xor(m, off, 64));
    if (lane == 0) red[w] = m;
    __syncthreads();
    m = fmaxf(fmaxf(red[0], red[1]), fmaxf(red[2], red[3]));
    float4 e;
    e.x = __expf(v.x - m); e.y = __expf(v.y - m);
    e.z = __expf(v.z - m); e.w = __expf(v.w - m);
    float s = e.x + e.y + e.z + e.w;
    for (int off = 32; off; off >>= 1) s += __shfl_xor(s, off, 64);
    __syncthreads();
    if (lane == 0) red[4 + w] = s;
    __syncthreads();
    float inv = 1.f / (red[4] + red[5] + red[6] + red[7]);
    e.x *= inv; e.y *= inv; e.z *= inv; e.w *= inv;
    ((float4*)p)[tid] = e;
}

// ---------------- wave partials of u: pbuf[b][c*4+w][h][d] = sum_{l in wave} a*h
// grid (4, 64): x = l-chunk of 256, y = b.  wave handles 64 contiguous l's.
__global__ __launch_bounds__(256) void wsum_kernel(const u16* __restrict__ h,
                                                   const float* __restrict__ scb,
                                                   float* __restrict__ pbuf) {
    __shared__ float as[8][256];
    const int b = blockIdx.y, c = blockIdx.x, tid = threadIdx.x;
    const int w = tid >> 6, lane = tid & 63;
    for (int i = tid; i < 2048; i += 256) {
        int hh = i >> 8, l = i & 255;
        as[hh][l] = scb[((size_t)b * 8 + hh) * 1024 + c * 256 + l];
    }
    __syncthreads();
    const u16* hb = h + ((size_t)b * 1024 + c * 256 + w * 64) * 512 + lane * 8;
    float acc[8][8] = {};
    for (int i = 0; i < 64; ++i) {
        u16x8 hv = *(const u16x8*)(hb + (size_t)i * 512);
        int l = w * 64 + i;
        float av[8];
        #pragma unroll
        for (int hh = 0; hh < 8; ++hh) av[hh] = as[hh][l];
        #pragma unroll
        for (int j = 0; j < 8; ++j) {
            float hf = b2f(hv[j]);
            #pragma unroll
            for (int hh = 0; hh < 8; ++hh) acc[hh][j] += av[hh] * hf;
        }
    }
    float* pw = pbuf + ((size_t)b * 16 + c * 4 + w) * 4096;
    #pragma unroll
    for (int hh = 0; hh < 8; ++hh) {
        float4 lo, hi;
        lo.x = acc[hh][0]; lo.y = acc[hh][1]; lo.z = acc[hh][2]; lo.w = acc[hh][3];
        hi.x = acc[hh][4]; hi.y = acc[hh][5]; hi.z = acc[hh][6]; hi.w = acc[hh][7];
        *(float4*)(pw + hh * 512 + lane * 8) = lo;
        *(float4*)(pw + hh * 512 + lane * 8 + 4) = hi;
    }
}

// ---------------- per-set: fold partials; ctx = u@Wv + bv; pooled = ctx@Wo + bo; LN -> y
__global__ __launch_bounds__(256) void pool_kernel(const float* __restrict__ pbuf,
                                                   const float* __restrict__ Wv,
                                                   const float* __restrict__ bv,
                                                   const float* __restrict__ Wo,
                                                   const float* __restrict__ bo,
                                                   const float* __restrict__ g,
                                                   const float* __restrict__ lb,
                                                   float* __restrict__ y) {
    __shared__ float us[8 * 512];
    __shared__ float ctx[512];
    __shared__ float red[8];
    __shared__ float stats[2];
    const int b = blockIdx.x, tid = threadIdx.x;
    for (int i = tid; i < 4096; i += 256) {
        float s = 0.f;
        #pragma unroll
        for (int c = 0; c < 16; ++c) s += pbuf[((size_t)b * 16 + c) * 4096 + i];
        us[i] = s;
    }
    __syncthreads();
    #pragma unroll
    for (int ph = 0; ph < 2; ++ph) {
        int e = tid + ph * 256;
        int hh = e >> 6;
        float acc = bv[e];
        for (int dd = 0; dd < 512; ++dd) acc += us[hh * 512 + dd] * Wv[(size_t)dd * 512 + e];
        ctx[e] = acc;
    }
    __syncthreads();
    float pv[2]; float psum = 0.f, psq = 0.f;
    #pragma unroll
    for (int ph = 0; ph < 2; ++ph) {
        int e2 = tid + ph * 256;
        float acc = bo[e2];
        for (int ee = 0; ee < 512; ++ee) acc += ctx[ee] * Wo[(size_t)ee * 512 + e2];
        pv[ph] = acc; psum += acc; psq += acc * acc;
    }
    for (int off = 32; off; off >>= 1) { psum += __shfl_xor(psum, off, 64); psq += __shfl_xor(psq, off, 64); }
    const int w = tid >> 6, lane = tid & 63;
    if (lane == 0) { red[w] = psum; red[4 + w] = psq; }
    __syncthreads();
    if (tid == 0) {
        float s = red[0] + red[1] + red[2] + red[3];
        float q2 = red[4] + red[5] + red[6] + red[7];
        float mu = s / 512.f;
        float var = q2 / 512.f - mu * mu;
        stats[0] = mu; stats[1] = 1.f / sqrtf(var + 1e-5f);
    }
    __syncthreads();
    #pragma unroll
    for (int ph = 0; ph < 2; ++ph) {
        int e2 = tid + ph * 256;
        y[(size_t)b * 512 + e2] = (pv[ph] - stats[0]) * stats[1] * g[e2] + lb[e2];
    }
}

// ---------------- head MLP layer 1: hid = relu(y@Wh1 + bh1)
__global__ __launch_bounds__(256) void h1_kernel(const float* __restrict__ y,
                                                 const float* __restrict__ Wh1,
                                                 const float* __restrict__ bh1,
                                                 float* __restrict__ hid) {
    __shared__ float ys[512];
    const int b = blockIdx.y, tid = threadIdx.x;
    ys[tid] = y[(size_t)b * 512 + tid];
    ys[tid + 256] = y[(size_t)b * 512 + tid + 256];
    __syncthreads();
    int j = blockIdx.x * 256 + tid;
    float acc = bh1[j];
    for (int dd = 0; dd < 512; ++dd) acc += ys[dd] * Wh1[(size_t)dd * 2048 + j];
    hid[(size_t)b * 2048 + j] = fmaxf(acc, 0.f);
}

// ---------------- head MLP layer 2: logits = hid@Wh2 + bh2
__global__ __launch_bounds__(256) void h2_kernel(const float* __restrict__ hid,
                                                 const float* __restrict__ Wh2,
                                                 const float* __restrict__ bh2,
                                                 float* __restrict__ out) {
    __shared__ float red[4];
    const int b = blockIdx.x, tid = threadIdx.x;
    float s = 0.f;
    for (int j = tid; j < 2048; j += 256) s += hid[(size_t)b * 2048 + j] * Wh2[j];
    for (int off = 32; off; off >>= 1) s += __shfl_xor(s, off, 64);
    const int w = tid >> 6, lane = tid & 63;
    if (lane == 0) red[w] = s;
    __syncthreads();
    if (tid == 0) out[b] = red[0] + red[1] + red[2] + red[3] + bh2[0];
}

extern "C" void kernel_launch(void* const* d_in, const int* in_sizes, int n_in,
                              void* d_out, int out_size, void* d_ws, size_t ws_size,
                              hipStream_t stream) {
    const int*   mut_idx = (const int*)d_in[0];
    const float* emb  = (const float*)d_in[2];
    const float* W1   = (const float*)d_in[3];
    const float* b1   = (const float*)d_in[4];
    const float* W2   = (const float*)d_in[5];
    const float* b2   = (const float*)d_in[6];
    const float* q    = (const float*)d_in[7];
    const float* Wq   = (const float*)d_in[8];
    const float* bq   = (const float*)d_in[9];
    const float* Wk   = (const float*)d_in[10];
    const float* bk   = (const float*)d_in[11];
    const float* Wv   = (const float*)d_in[12];
    const float* bv   = (const float*)d_in[13];
    const float* Wo   = (const float*)d_in[14];
    const float* bo   = (const float*)d_in[15];
    const float* ln_g = (const float*)d_in[16];
    const float* ln_b = (const float*)d_in[17];
    const float* Wh1  = (const float*)d_in[18];
    const float* bh1  = (const float*)d_in[19];
    const float* Wh2  = (const float*)d_in[20];
    const float* bh2  = (const float*)d_in[21];
    float* out = (float*)d_out;

    // fixed-footprint allocations (256B aligned)
    char* p = (char*)d_ws;
    auto alloc = [&](size_t bytes) {
        char* r = p; p += (bytes + 255) & ~(size_t)255; return r;
    };
    u16*  W1t  = (u16*)alloc((size_t)H_ * D_ * 2);      // [2048][512] bf16
    u16*  W2t  = (u16*)alloc((size_t)D_ * H_ * 2);      // [512][2048] bf16
    float* qp  = (float*)alloc(D_ * 4);
    float* wke = (float*)alloc((size_t)D_ * NH_ * 4);
    float* cke = (float*)alloc(NH_ * 4);
    float* scb  = (float*)alloc((size_t)B_ * NH_ * L_ * 4);        // scores/attn weights
    float* pbuf = (float*)alloc((size_t)B_ * 16 * NH_ * D_ * 4);   // wave partials of u
    float* ybuf = (float*)alloc((size_t)B_ * D_ * 4);
    float* hid  = (float*)alloc((size_t)B_ * H_ * 4);
    u16*  hbuf = (u16*)alloc((size_t)TOT * D_ * 2);     // full h, bf16

    size_t fixed = (size_t)(p - (char*)d_ws);
    // adaptive chunk: z (CH*1024 B) + C1 (CH*4096 B)
    int CH = 65536;
    while (CH > 1024 && fixed + (size_t)CH * 5120 + 8192 > ws_size) CH >>= 1;
    u16* z  = (u16*)alloc((size_t)CH * D_ * 2);
    u16* C1 = (u16*)alloc((size_t)CH * H_ * 2);

    // weight conversion / folding
    transpose_cvt<<<dim3(H_ / 32, D_ / 32), dim3(32, 8), 0, stream>>>(W1, W1t, D_, H_);
    transpose_cvt<<<dim3(D_ / 32, H_ / 32), dim3(32, 8), 0, stream>>>(W2, W2t, H_, D_);
    qp_kernel<<<2, 256, 0, stream>>>(q, Wq, bq, qp);
    wke_kernel<<<16, 256, 0, stream>>>(Wk, bk, qp, wke, cke);

    // phi MLP over token chunks
    for (int c = 0; c * CH < TOT; ++c) {
        embed_kernel<<<CH / 4, 256, 0, stream>>>(mut_idx + c * CH, emb, z);
        gemm_bt<1><<<dim3(H_ / 128, CH / 128), 256, 0, stream>>>(z, W1t, b1, C1, H_, D_);
        gemm_bt<0><<<dim3(D_ / 128, CH / 128), 256, 0, stream>>>(C1, W2t, b2,
                                                                 hbuf + (size_t)c * CH * D_, D_, H_);
    }

    // attention pool + head
    score_kernel<<<dim3(16, B_), 256, 0, stream>>>(hbuf, wke, cke, scb);
    softmax_kernel<<<B_ * NH_, 256, 0, stream>>>(scb);
    wsum_kernel<<<dim3(4, B_), 256, 0, stream>>>(hbuf, scb, pbuf);
    pool_kernel<<<B_, 256, 0, stream>>>(pbuf, Wv, bv, Wo, bo, ln_g, ln_b, ybuf);
    h1_kernel<<<dim3(H_ / 256, B_), 256, 0, stream>>>(ybuf, Wh1, bh1, hid);
    h2_kernel<<<B_, 256, 0, stream>>>(hid, Wh2, bh2, out);
}

// Round 3
// 940.686 us; speedup vs baseline: 1.3287x; 1.0083x over previous
//
#include <hip/hip_runtime.h>
#include <hip/hip_bf16.h>

using u16 = unsigned short;
typedef __bf16 bf16x8_t __attribute__((ext_vector_type(8)));
typedef float    f32x4  __attribute__((ext_vector_type(4)));
typedef unsigned short u16x8 __attribute__((ext_vector_type(8)));

#define B_  64
#define L_  1024
#define TOT 65536
#define D_  512
#define H_  2048
#define NH_ 8

__device__ __forceinline__ float b2f(u16 x) {
    union { unsigned int i; float f; } v; v.i = ((unsigned int)x) << 16; return v.f;
}
__device__ __forceinline__ u16 f2b(float f) {
    union { float f; unsigned int i; } v; v.f = f;
    unsigned int i = v.i;
    unsigned int r = i + 0x7FFFu + ((i >> 16) & 1u);   // RNE
    return (u16)(r >> 16);
}

// ---------------- transpose + fp32->bf16 convert:  in[R][C] f32 -> out[C][R] bf16
__global__ __launch_bounds__(256) void transpose_cvt(const float* __restrict__ in,
                                                     u16* __restrict__ out, int R, int C) {
    __shared__ float tile[32][33];
    int c0 = blockIdx.x * 32, r0 = blockIdx.y * 32;
    int tx = threadIdx.x, ty = threadIdx.y;
    #pragma unroll
    for (int i = 0; i < 4; ++i)
        tile[ty + 8 * i][tx] = in[(size_t)(r0 + ty + 8 * i) * C + c0 + tx];
    __syncthreads();
    #pragma unroll
    for (int i = 0; i < 4; ++i)
        out[(size_t)(c0 + ty + 8 * i) * R + r0 + tx] = f2b(tile[tx][ty + 8 * i]);
}

// ---------------- qp = q @ Wq + bq   (512 outputs, 2 blocks)
__global__ __launch_bounds__(256) void qp_kernel(const float* __restrict__ q,
                                                 const float* __restrict__ Wq,
                                                 const float* __restrict__ bq,
                                                 float* __restrict__ qp) {
    __shared__ float qs[512];
    int tid = threadIdx.x;
    qs[tid] = q[tid]; qs[tid + 256] = q[tid + 256];
    __syncthreads();
    int j = blockIdx.x * 256 + tid;
    float acc = bq[j];
    for (int d = 0; d < 512; ++d) acc += qs[d] * Wq[(size_t)d * 512 + j];
    qp[j] = acc;
}

// ---------------- wke[d][h] = 0.125 * sum_j Wk[d, h*64+j]*qp[h*64+j];  cke[h] from bk
__global__ __launch_bounds__(256) void wke_kernel(const float* __restrict__ Wk,
                                                  const float* __restrict__ bk,
                                                  const float* __restrict__ qp,
                                                  float* __restrict__ wke,
                                                  float* __restrict__ cke) {
    __shared__ float qs[512];
    int tid = threadIdx.x;
    qs[tid] = qp[tid]; qs[tid + 256] = qp[tid + 256];
    __syncthreads();
    int d = blockIdx.x * 32 + (tid >> 3);
    int h = tid & 7;
    float s = 0.f;
    for (int j = 0; j < 64; ++j) s += Wk[(size_t)d * 512 + h * 64 + j] * qs[h * 64 + j];
    wke[d * 8 + h] = 0.125f * s;
    if (blockIdx.x == 0 && tid < 8) {
        float c = 0.f;
        for (int j = 0; j < 64; ++j) c += bk[tid * 64 + j] * qs[tid * 64 + j];
        cke[tid] = 0.125f * c;
    }
}

// ---------------- gather emb rows -> bf16 z chunk
__global__ __launch_bounds__(256) void embed_kernel(const int* __restrict__ idx,
                                                    const float* __restrict__ emb,
                                                    u16* __restrict__ z) {
    int u = blockIdx.x * 256 + threadIdx.x;   // one unit = 8 elements
    int t = u >> 6;                            // 64 units per 512-wide row
    int d0 = (u & 63) * 8;
    int row = idx[t];
    const float4* src = (const float4*)(emb + (size_t)row * 512 + d0);
    float4 a = src[0], b = src[1];
    u16x8 o;
    o[0] = f2b(a.x); o[1] = f2b(a.y); o[2] = f2b(a.z); o[3] = f2b(a.w);
    o[4] = f2b(b.x); o[5] = f2b(b.y); o[6] = f2b(b.z); o[7] = f2b(b.w);
    *(u16x8*)(z + (size_t)t * 512 + d0) = o;
}

// ---------------- m97-style bf16 GEMM:  C[M,N] = act(A[M,K] @ Bt[N,K]^T + bias)
// 1D grid with XCD-aware swizzle: all n-tiles of one m-row land on one XCD,
// consecutively -> each A row-block fetched by exactly one XCD L2.
// LDS XOR swizzle: physical colgroup g holds global group g^((row>>1)&3) ->
// ds_read_b128 lanes spread 2-way across all 8 bank-quads (2-way is free).
template <int RELU, int LNT>
__global__ __launch_bounds__(256) void gemm_bt(const u16* __restrict__ A,
                                               const u16* __restrict__ Bt,
                                               const float* __restrict__ bias,
                                               u16* __restrict__ C,
                                               int N, int K) {
    __shared__ __align__(16) u16 As[128 * 32];
    __shared__ __align__(16) u16 Bs[128 * 32];
    const int tid = threadIdx.x;
    const int id = blockIdx.x;
    const int xcd = id & 7, s = id >> 3;
    const int n_idx = s & ((1 << LNT) - 1);
    const int m_idx = xcd + 8 * (s >> LNT);
    const int m0 = m_idx * 128, n0 = n_idx * 128;
    const int lane = tid & 63, quad = lane >> 4, l15 = lane & 15;
    const int wave = tid >> 6, wm = wave >> 1, wn = wave & 1;

    f32x4 acc[4][4] = {};

    const int nK = K >> 5;
    for (int kt = 0; kt < nK; ++kt) {
        __syncthreads();
        const int kb = kt * 32;
        #pragma unroll
        for (int r = 0; r < 2; ++r) {
            int u = tid + r * 256;
            int cg = (u & 3) ^ ((u >> 3) & 3);   // global colgroup for this LDS slot
            const u16* ga = A + (size_t)(m0 + (u >> 2)) * K + kb + cg * 8;
            __builtin_amdgcn_global_load_lds((const __attribute__((address_space(1))) void*)ga,
                                             (__attribute__((address_space(3))) void*)(&As[u * 8]),
                                             16, 0, 0);
            const u16* gb = Bt + (size_t)(n0 + (u >> 2)) * K + kb + cg * 8;
            __builtin_amdgcn_global_load_lds((const __attribute__((address_space(1))) void*)gb,
                                             (__attribute__((address_space(3))) void*)(&Bs[u * 8]),
                                             16, 0, 0);
        }
        __syncthreads();
        bf16x8_t af[4], bfr[4];
        #pragma unroll
        for (int mt = 0; mt < 4; ++mt) {
            int row = wm * 64 + mt * 16 + l15;
            int g = quad ^ ((row >> 1) & 3);
            af[mt] = *(const bf16x8_t*)&As[row * 32 + g * 8];
        }
        #pragma unroll
        for (int nt = 0; nt < 4; ++nt) {
            int row = wn * 64 + nt * 16 + l15;
            int g = quad ^ ((row >> 1) & 3);
            bfr[nt] = *(const bf16x8_t*)&Bs[row * 32 + g * 8];
        }
        #pragma unroll
        for (int mt = 0; mt < 4; ++mt)
            #pragma unroll
            for (int nt = 0; nt < 4; ++nt)
                acc[mt][nt] = __builtin_amdgcn_mfma_f32_16x16x32_bf16(af[mt], bfr[nt],
                                                                      acc[mt][nt], 0, 0, 0);
    }

    float bvv[4];
    #pragma unroll
    for (int nt = 0; nt < 4; ++nt) bvv[nt] = bias[n0 + wn * 64 + nt * 16 + l15];
    #pragma unroll
    for (int mt = 0; mt < 4; ++mt)
        #pragma unroll
        for (int nt = 0; nt < 4; ++nt)
            #pragma unroll
            for (int r = 0; r < 4; ++r) {
                int row = m0 + wm * 64 + mt * 16 + quad * 4 + r;
                int col = n0 + wn * 64 + nt * 16 + l15;
                float v = acc[mt][nt][r] + bvv[nt];
                if (RELU) v = fmaxf(v, 0.f);
                C[(size_t)row * N + col] = f2b(v);
            }
}

// ---------------- scores[b][h][l] = h[b,l,:] . wke[:,h] + cke[h]
__global__ __launch_bounds__(256) void score_kernel(const u16* __restrict__ h,
                                                    const float* __restrict__ wke,
                                                    const float* __restrict__ cke,
                                                    float* __restrict__ scb) {
    const int b = blockIdx.y, lc = blockIdx.x, tid = threadIdx.x;
    const int w = tid >> 6, lane = tid & 63;

    float wkr[8][8];
    #pragma unroll
    for (int j = 0; j < 8; ++j)
        #pragma unroll
        for (int hh = 0; hh < 8; ++hh) wkr[j][hh] = wke[(lane * 8 + j) * 8 + hh];
    float cr[8];
    #pragma unroll
    for (int hh = 0; hh < 8; ++hh) cr[hh] = cke[hh];

    const u16* hb = h + (size_t)b * 1024 * 512;

    #pragma unroll 2
    for (int i = 0; i < 16; ++i) {
        int l = lc * 64 + w * 16 + i;
        u16x8 hv = *(const u16x8*)(hb + (size_t)l * 512 + lane * 8);
        float s[8] = {0, 0, 0, 0, 0, 0, 0, 0};
        #pragma unroll
        for (int j = 0; j < 8; ++j) {
            float hf = b2f(hv[j]);
            #pragma unroll
            for (int hh = 0; hh < 8; ++hh) s[hh] += hf * wkr[j][hh];
        }
        #pragma unroll
        for (int hh = 0; hh < 8; ++hh) {
            float v = s[hh];
            for (int off = 32; off; off >>= 1) v += __shfl_xor(v, off, 64);
            if (lane == 0) scb[((size_t)b * 8 + hh) * 1024 + l] = v + cr[hh];
        }
    }
}

// ---------------- softmax over l for each (b,h); in-place on scb. grid 512.
__global__ __launch_bounds__(256) void softmax_kernel(float* __restrict__ scb) {
    __shared__ float red[8];
    const int bh = blockIdx.x, tid = threadIdx.x;
    const int w = tid >> 6, lane = tid & 63;
    float* p = scb + (size_t)bh * 1024;
    float4 v = ((float4*)p)[tid];
    float m = fmaxf(fmaxf(v.x, v.y), fmaxf(v.z, v.w));
    for (int off = 32; off; off >>= 1) m = fmaxf(m, __shfl_xor(m, off, 64));
    if (lane == 0) red[w] = m;
    __syncthreads();
    m = fmaxf(fmaxf(red[0], red[1]), fmaxf(red[2], red[3]));
    float4 e;
    e.x = __expf(v.x - m); e.y = __expf(v.y - m);
    e.z = __expf(v.z - m); e.w = __expf(v.w - m);
    float s = e.x + e.y + e.z + e.w;
    for (int off = 32; off; off >>= 1) s += __shfl_xor(s, off, 64);
    __syncthreads();
    if (lane == 0) red[4 + w] = s;
    __syncthreads();
    float inv = 1.f / (red[4] + red[5] + red[6] + red[7]);
    e.x *= inv; e.y *= inv; e.z *= inv; e.w *= inv;
    ((float4*)p)[tid] = e;
}

// ---------------- wave partials of u
__global__ __launch_bounds__(256) void wsum_kernel(const u16* __restrict__ h,
                                                   const float* __restrict__ scb,
                                                   float* __restrict__ pbuf) {
    __shared__ float as[8][256];
    const int b = blockIdx.y, c = blockIdx.x, tid = threadIdx.x;
    const int w = tid >> 6, lane = tid & 63;
    for (int i = tid; i < 2048; i += 256) {
        int hh = i >> 8, l = i & 255;
        as[hh][l] = scb[((size_t)b * 8 + hh) * 1024 + c * 256 + l];
    }
    __syncthreads();
    const u16* hb = h + ((size_t)b * 1024 + c * 256 + w * 64) * 512 + lane * 8;
    float acc[8][8] = {};
    for (int i = 0; i < 64; ++i) {
        u16x8 hv = *(const u16x8*)(hb + (size_t)i * 512);
        int l = w * 64 + i;
        float av[8];
        #pragma unroll
        for (int hh = 0; hh < 8; ++hh) av[hh] = as[hh][l];
        #pragma unroll
        for (int j = 0; j < 8; ++j) {
            float hf = b2f(hv[j]);
            #pragma unroll
            for (int hh = 0; hh < 8; ++hh) acc[hh][j] += av[hh] * hf;
        }
    }
    float* pw = pbuf + ((size_t)b * 16 + c * 4 + w) * 4096;
    #pragma unroll
    for (int hh = 0; hh < 8; ++hh) {
        float4 lo, hi;
        lo.x = acc[hh][0]; lo.y = acc[hh][1]; lo.z = acc[hh][2]; lo.w = acc[hh][3];
        hi.x = acc[hh][4]; hi.y = acc[hh][5]; hi.z = acc[hh][6]; hi.w = acc[hh][7];
        *(float4*)(pw + hh * 512 + lane * 8) = lo;
        *(float4*)(pw + hh * 512 + lane * 8 + 4) = hi;
    }
}

// ---------------- per-set: fold partials; ctx = u@Wv + bv; pooled = ctx@Wo + bo; LN -> y
__global__ __launch_bounds__(256) void pool_kernel(const float* __restrict__ pbuf,
                                                   const float* __restrict__ Wv,
                                                   const float* __restrict__ bv,
                                                   const float* __restrict__ Wo,
                                                   const float* __restrict__ bo,
                                                   const float* __restrict__ g,
                                                   const float* __restrict__ lb,
                                                   float* __restrict__ y) {
    __shared__ float us[8 * 512];
    __shared__ float ctx[512];
    __shared__ float red[8];
    __shared__ float stats[2];
    const int b = blockIdx.x, tid = threadIdx.x;
    for (int i = tid; i < 4096; i += 256) {
        float s = 0.f;
        #pragma unroll
        for (int c = 0; c < 16; ++c) s += pbuf[((size_t)b * 16 + c) * 4096 + i];
        us[i] = s;
    }
    __syncthreads();
    #pragma unroll
    for (int ph = 0; ph < 2; ++ph) {
        int e = tid + ph * 256;
        int hh = e >> 6;
        float acc = bv[e];
        for (int dd = 0; dd < 512; ++dd) acc += us[hh * 512 + dd] * Wv[(size_t)dd * 512 + e];
        ctx[e] = acc;
    }
    __syncthreads();
    float pv[2]; float psum = 0.f, psq = 0.f;
    #pragma unroll
    for (int ph = 0; ph < 2; ++ph) {
        int e2 = tid + ph * 256;
        float acc = bo[e2];
        for (int ee = 0; ee < 512; ++ee) acc += ctx[ee] * Wo[(size_t)ee * 512 + e2];
        pv[ph] = acc; psum += acc; psq += acc * acc;
    }
    for (int off = 32; off; off >>= 1) { psum += __shfl_xor(psum, off, 64); psq += __shfl_xor(psq, off, 64); }
    const int w = tid >> 6, lane = tid & 63;
    if (lane == 0) { red[w] = psum; red[4 + w] = psq; }
    __syncthreads();
    if (tid == 0) {
        float s = red[0] + red[1] + red[2] + red[3];
        float q2 = red[4] + red[5] + red[6] + red[7];
        float mu = s / 512.f;
        float var = q2 / 512.f - mu * mu;
        stats[0] = mu; stats[1] = 1.f / sqrtf(var + 1e-5f);
    }
    __syncthreads();
    #pragma unroll
    for (int ph = 0; ph < 2; ++ph) {
        int e2 = tid + ph * 256;
        y[(size_t)b * 512 + e2] = (pv[ph] - stats[0]) * stats[1] * g[e2] + lb[e2];
    }
}

// ---------------- head MLP layer 1: hid = relu(y@Wh1 + bh1)
__global__ __launch_bounds__(256) void h1_kernel(const float* __restrict__ y,
                                                 const float* __restrict__ Wh1,
                                                 const float* __restrict__ bh1,
                                                 float* __restrict__ hid) {
    __shared__ float ys[512];
    const int b = blockIdx.y, tid = threadIdx.x;
    ys[tid] = y[(size_t)b * 512 + tid];
    ys[tid + 256] = y[(size_t)b * 512 + tid + 256];
    __syncthreads();
    int j = blockIdx.x * 256 + tid;
    float acc = bh1[j];
    for (int dd = 0; dd < 512; ++dd) acc += ys[dd] * Wh1[(size_t)dd * 2048 + j];
    hid[(size_t)b * 2048 + j] = fmaxf(acc, 0.f);
}

// ---------------- head MLP layer 2: logits = hid@Wh2 + bh2
__global__ __launch_bounds__(256) void h2_kernel(const float* __restrict__ hid,
                                                 const float* __restrict__ Wh2,
                                                 const float* __restrict__ bh2,
                                                 float* __restrict__ out) {
    __shared__ float red[4];
    const int b = blockIdx.x, tid = threadIdx.x;
    float s = 0.f;
    for (int j = tid; j < 2048; j += 256) s += hid[(size_t)b * 2048 + j] * Wh2[j];
    for (int off = 32; off; off >>= 1) s += __shfl_xor(s, off, 64);
    const int w = tid >> 6, lane = tid & 63;
    if (lane == 0) red[w] = s;
    __syncthreads();
    if (tid == 0) out[b] = red[0] + red[1] + red[2] + red[3] + bh2[0];
}

extern "C" void kernel_launch(void* const* d_in, const int* in_sizes, int n_in,
                              void* d_out, int out_size, void* d_ws, size_t ws_size,
                              hipStream_t stream) {
    const int*   mut_idx = (const int*)d_in[0];
    const float* emb  = (const float*)d_in[2];
    const float* W1   = (const float*)d_in[3];
    const float* b1   = (const float*)d_in[4];
    const float* W2   = (const float*)d_in[5];
    const float* b2   = (const float*)d_in[6];
    const float* q    = (const float*)d_in[7];
    const float* Wq   = (const float*)d_in[8];
    const float* bq   = (const float*)d_in[9];
    const float* Wk   = (const float*)d_in[10];
    const float* bk   = (const float*)d_in[11];
    const float* Wv   = (const float*)d_in[12];
    const float* bv   = (const float*)d_in[13];
    const float* Wo   = (const float*)d_in[14];
    const float* bo   = (const float*)d_in[15];
    const float* ln_g = (const float*)d_in[16];
    const float* ln_b = (const float*)d_in[17];
    const float* Wh1  = (const float*)d_in[18];
    const float* bh1  = (const float*)d_in[19];
    const float* Wh2  = (const float*)d_in[20];
    const float* bh2  = (const float*)d_in[21];
    float* out = (float*)d_out;

    // fixed-footprint allocations (256B aligned)
    char* p = (char*)d_ws;
    auto alloc = [&](size_t bytes) {
        char* r = p; p += (bytes + 255) & ~(size_t)255; return r;
    };
    u16*  W1t  = (u16*)alloc((size_t)H_ * D_ * 2);      // [2048][512] bf16
    u16*  W2t  = (u16*)alloc((size_t)D_ * H_ * 2);      // [512][2048] bf16
    float* qp  = (float*)alloc(D_ * 4);
    float* wke = (float*)alloc((size_t)D_ * NH_ * 4);
    float* cke = (float*)alloc(NH_ * 4);
    float* scb  = (float*)alloc((size_t)B_ * NH_ * L_ * 4);        // scores/attn weights
    float* pbuf = (float*)alloc((size_t)B_ * 16 * NH_ * D_ * 4);   // wave partials of u
    float* ybuf = (float*)alloc((size_t)B_ * D_ * 4);
    float* hid  = (float*)alloc((size_t)B_ * H_ * 4);
    u16*  hbuf = (u16*)alloc((size_t)TOT * D_ * 2);     // full h, bf16

    size_t fixed = (size_t)(p - (char*)d_ws);
    // adaptive chunk: z (CH*1024 B) + C1 (CH*4096 B)
    int CH = 65536;
    while (CH > 1024 && fixed + (size_t)CH * 5120 + 8192 > ws_size) CH >>= 1;
    u16* z  = (u16*)alloc((size_t)CH * D_ * 2);
    u16* C1 = (u16*)alloc((size_t)CH * H_ * 2);

    // weight conversion / folding
    transpose_cvt<<<dim3(H_ / 32, D_ / 32), dim3(32, 8), 0, stream>>>(W1, W1t, D_, H_);
    transpose_cvt<<<dim3(D_ / 32, H_ / 32), dim3(32, 8), 0, stream>>>(W2, W2t, H_, D_);
    qp_kernel<<<2, 256, 0, stream>>>(q, Wq, bq, qp);
    wke_kernel<<<16, 256, 0, stream>>>(Wk, bk, qp, wke, cke);

    // phi MLP over token chunks  (m-tiles per chunk is CH/128 >= 8, divisible by 8)
    for (int c = 0; c * CH < TOT; ++c) {
        embed_kernel<<<CH / 4, 256, 0, stream>>>(mut_idx + c * CH, emb, z);
        gemm_bt<1, 4><<<dim3((CH / 128) * 16), 256, 0, stream>>>(z, W1t, b1, C1, H_, D_);
        gemm_bt<0, 2><<<dim3((CH / 128) * 4), 256, 0, stream>>>(C1, W2t, b2,
                                                                hbuf + (size_t)c * CH * D_, D_, H_);
    }

    // attention pool + head
    score_kernel<<<dim3(16, B_), 256, 0, stream>>>(hbuf, wke, cke, scb);
    softmax_kernel<<<B_ * NH_, 256, 0, stream>>>(scb);
    wsum_kernel<<<dim3(4, B_), 256, 0, stream>>>(hbuf, scb, pbuf);
    pool_kernel<<<B_, 256, 0, stream>>>(pbuf, Wv, bv, Wo, bo, ln_g, ln_b, ybuf);
    h1_kernel<<<dim3(H_ / 256, B_), 256, 0, stream>>>(ybuf, Wh1, bh1, hid);
    h2_kernel<<<B_, 256, 0, stream>>>(hid, Wh2, bh2, out);
}